// Round 2
// baseline (482.998 us; speedup 1.0000x reference)
//
#include <hip/hip_runtime.h>

// Fused LSTM: B=16384, T=60, IN=1, H=50, OUT=1.
// 256 WGs x 512 threads (8 waves). lane = batch element (64/WG).
// Wave w owns hidden units j = w + 8m; each thread computes all 4 gate rows
// for its units -> c-update register-local.
// Round 2: weights read via the SCALAR path (uniform global indices ->
// s_load into SGPRs, consumed as v_fmac v,s,v). LDS only carries the h
// exchange + a one-time staged x. Round-1 showed the LDS-broadcast of
// weights (1 KiB return per wave-uniform ds_read_b128) was the bottleneck:
// ~2.6 MB/step/CU through the 128 B/clk LDS pipe == the entire 543 us.

namespace {
constexpr int BTOT = 16384;
constexpr int TS = 60;
constexpr int HID = 50;
constexpr int NB = 64;       // batch per workgroup
constexpr int XP = NB + 1;   // padded x-stage row (conflict-free write+read)

__device__ __forceinline__ float fexp2(float x) {
#if __has_builtin(__builtin_amdgcn_exp2f)
  return __builtin_amdgcn_exp2f(x);
#else
  return exp2f(x);
#endif
}
__device__ __forceinline__ float frcp(float x) {
#if __has_builtin(__builtin_amdgcn_rcpf)
  return __builtin_amdgcn_rcpf(x);
#else
  return 1.0f / x;
#endif
}
__device__ __forceinline__ float sigm(float x) {
  return frcp(1.0f + fexp2(-1.4426950408889634f * x));
}
__device__ __forceinline__ float tanh_(float x) {
  return fmaf(-2.0f, frcp(1.0f + fexp2(2.8853900817779268f * x)), 1.0f);
}
}  // namespace

__global__ __launch_bounds__(512, 2) void lstm_fused(
    const float* __restrict__ x,      // [B][60]
    const float* __restrict__ w_ih,   // [200]
    const float* __restrict__ w_hh,   // [200][50]
    const float* __restrict__ b_ih,   // [200]
    const float* __restrict__ b_hh,   // [200]
    const float* __restrict__ w_lin,  // [3000] = [t*50+j]
    const float* __restrict__ b_lin,  // [1]
    float* __restrict__ out)          // [B]
{
  __shared__ float hbuf[HID * NB];  // [k][b]  12.8 KB
  __shared__ float xlds[TS * XP];   // [t][b]  15.6 KB

  const int tid = threadIdx.x;
  const int lane = tid & 63;
  const int wv = __builtin_amdgcn_readfirstlane(tid >> 6);  // uniform wave id

  // One-time coalesced stage of this WG's x slice, transposed to [t][b].
  // Write addr = t*65+b: consecutive t (fixed b) -> consecutive banks.
  const long bbase = (long)blockIdx.x * NB;
  for (int idx = tid; idx < NB * TS; idx += 512) {
    const int b = idx / TS;
    const int t = idx - b * TS;
    xlds[t * XP + b] = x[(bbase + b) * TS + t];
  }
  __syncthreads();

  float h[HID];
#pragma unroll
  for (int k = 0; k < HID; ++k) h[k] = 0.0f;
  float c[7];
#pragma unroll
  for (int m = 0; m < 7; ++m) c[m] = 0.0f;
  float oacc = 0.0f;

#pragma unroll 1
  for (int t = 0; t < TS; ++t) {
    const float xv = xlds[t * XP + lane];  // stride-1 banks, conflict-free

#pragma unroll
    for (int m = 0; m < 7; ++m) {
      const int j = wv + 8 * m;  // wave-uniform
      if (j < HID) {             // uniform branch
        const int ri = j, rf = HID + j, rg = 2 * HID + j, ro = 3 * HID + j;
        // x-projection + biases: uniform scalar loads
        float ai = fmaf(xv, w_ih[ri], b_ih[ri] + b_hh[ri]);
        float af = fmaf(xv, w_ih[rf], b_ih[rf] + b_hh[rf]);
        float ag = fmaf(xv, w_ih[rg], b_ih[rg] + b_hh[rg]);
        float ao = fmaf(xv, w_ih[ro], b_ih[ro] + b_hh[ro]);
        // recurrent matmul: weights via scalar path (uniform addresses),
        // h via per-lane registers. v_fmac_f32 v, s, v.
        const float* __restrict__ wi = w_hh + ri * HID;
        const float* __restrict__ wf = w_hh + rf * HID;
        const float* __restrict__ wg = w_hh + rg * HID;
        const float* __restrict__ wo = w_hh + ro * HID;
#pragma unroll
        for (int k = 0; k < HID; ++k) {
          const float hk = h[k];
          ai = fmaf(wi[k], hk, ai);
          af = fmaf(wf[k], hk, af);
          ag = fmaf(wg[k], hk, ag);
          ao = fmaf(wo[k], hk, ao);
        }
        const float ig = sigm(ai);
        const float fg = sigm(af);
        const float gg = tanh_(ag);
        const float og = sigm(ao);
        const float cn = fmaf(fg, c[m], ig * gg);
        c[m] = cn;
        const float hn = og * tanh_(cn);
        hbuf[j * NB + lane] = hn;                   // stride-1, conflict-free
        oacc = fmaf(hn, w_lin[t * HID + j], oacc);  // uniform scalar load
      }
    }
    __syncthreads();
#pragma unroll
    for (int k = 0; k < HID; ++k) h[k] = hbuf[k * NB + lane];
    __syncthreads();
  }

  // reduce per-wave output partials (reuse hbuf; all reads of h are done)
  hbuf[wv * NB + lane] = oacc;
  __syncthreads();
  if (tid < NB) {
    float s = b_lin[0];
#pragma unroll
    for (int q = 0; q < 8; ++q) s += hbuf[q * NB + tid];
    out[(long)blockIdx.x * NB + tid] = s;
  }
}

extern "C" void kernel_launch(void* const* d_in, const int* in_sizes, int n_in,
                              void* d_out, int out_size, void* d_ws, size_t ws_size,
                              hipStream_t stream) {
  const float* x     = (const float*)d_in[0];
  const float* w_ih  = (const float*)d_in[1];
  const float* w_hh  = (const float*)d_in[2];
  const float* b_ih  = (const float*)d_in[3];
  const float* b_hh  = (const float*)d_in[4];
  const float* w_lin = (const float*)d_in[5];
  const float* b_lin = (const float*)d_in[6];
  float* out = (float*)d_out;

  dim3 grid(BTOT / NB);  // 256 workgroups -> one per CU
  dim3 block(512);
  lstm_fused<<<grid, block, 0, stream>>>(x, w_ih, w_hh, b_ih, b_hh, w_lin,
                                         b_lin, out);
}

// Round 3
// 122.997 us; speedup vs baseline: 3.9269x; 3.9269x over previous
//
#include <hip/hip_runtime.h>

// Fused LSTM B=16384, T=60, IN=1, H=50, OUT=1 — MFMA version.
// 512 WGs x 512 thr; 32 batches/WG. Per step: C'[208 gate-rows][32 b] =
// W'[rows permuted: 16T+4g+reg <-> gate reg of unit u=16g+T][K=64] x
// H[K=64][32 b], via mfma_f32_16x16x32_f16, 3-product hi/lo fp16 split
// (fp32-equivalent). W' frags live in VGPRs (loaded once). K-cols: 0..49=h,
// 50..61=0, 62=bias(.1), 63=w_ih(.x). Each lane's 4 D-regs = i,f,g,o of one
// unit for one batch -> elementwise fully register-local. H double-buffered
// fp16 hi/lo in LDS, XOR-swizzled rows, 1 barrier/step.

namespace {
constexpr int TS = 60;
constexpr int NBW = 32;  // batches per WG

typedef _Float16 half8 __attribute__((ext_vector_type(8)));
typedef _Float16 half4 __attribute__((ext_vector_type(4)));
typedef float f32x4 __attribute__((ext_vector_type(4)));

// LDS union (64 KB): prologue W'' f32[256][64]; steady:
constexpr int OFF_H = 0;       // 4 x 5120 B: Hhi0,Hlo0,Hhi1,Hlo1 ([32 b][80 halves])
constexpr int OFF_X = 20480;   // f32[60][33]
constexpr int OFF_WL = 28416;  // f32[60][64]
constexpr int OFF_OB = 43776;  // f32[16][32]

__device__ __forceinline__ float fexp2(float x) { return __builtin_amdgcn_exp2f(x); }
__device__ __forceinline__ float frcp(float x) { return __builtin_amdgcn_rcpf(x); }
__device__ __forceinline__ float sigm(float x) {
  return frcp(1.0f + fexp2(-1.4426950408889634f * x));
}
__device__ __forceinline__ float tanh_(float x) {
  return fmaf(-2.0f, frcp(1.0f + fexp2(2.8853900817779268f * x)), 1.0f);
}
// swizzle byte-offset-in-row: XOR 16B-chunk index with (b&7) — applied to
// ALL H accesses (writes and B-frag reads) so it's a consistent involution.
__device__ __forceinline__ int hswz(int b, int ko) {
  return (ko & 15) | (((ko >> 4) ^ (b & 7)) << 4);
}
__device__ __forceinline__ f32x4 mfma16(half8 a, half8 b, f32x4 c) {
  return __builtin_amdgcn_mfma_f32_16x16x32_f16(a, b, c, 0, 0, 0);
}
}  // namespace

__global__ __launch_bounds__(512, 4) void lstm_mfma(
    const float* __restrict__ x,      // [B][60]
    const float* __restrict__ w_ih,   // [200]
    const float* __restrict__ w_hh,   // [200][50]
    const float* __restrict__ b_ih,   // [200]
    const float* __restrict__ b_hh,   // [200]
    const float* __restrict__ w_lin,  // [3000]
    const float* __restrict__ b_lin,  // [1]
    float* __restrict__ out)          // [B]
{
  __shared__ __align__(16) char smem[65536];

  const int tid = threadIdx.x;
  const int lane = tid & 63;
  const int wv = tid >> 6;     // 0..7
  const int wm4 = wv & 3;      // M-tile group (tiles 4*wm4..+3)
  const int wn = wv >> 2;      // batch half
  const int g = lane >> 4;     // lane quad-group
  const int cl = lane & 15;
  const int b = wn * 16 + cl;  // batch-in-WG 0..31
  const long bbase = (long)blockIdx.x * NBW;

  // ---- stage W'' = permuted/extended weights, f32[256][64] ----
  float* W2 = (float*)smem;
  for (int idx = tid; idx < 256 * 64; idx += 512) {
    const int rp = idx >> 6, k = idx & 63;
    const int u = 16 * ((rp >> 2) & 3) + (rp >> 4);  // unit
    const int reg = rp & 3;                          // gate (i,f,g,o)
    float v = 0.0f;
    if (u < 50) {
      const int orig = reg * 50 + u;
      if (k < 50) v = w_hh[orig * 50 + k];
      else if (k == 62) v = b_ih[orig] + b_hh[orig];
      else if (k == 63) v = w_ih[orig];
    }
    W2[idx] = v;
  }
  __syncthreads();

  // ---- gather A-fragments (held in VGPRs for all 60 steps) ----
  // A layout 16x16x32: lane holds row=l&15, k = 32*kc + 8*(l>>4) + e.
  half8 ahi[4][2], alo[4][2];
#pragma unroll
  for (int tau = 0; tau < 4; ++tau) {
    const int T = 4 * wm4 + tau;
#pragma unroll
    for (int kc = 0; kc < 2; ++kc) {
      const float* wr = W2 + (16 * T + cl) * 64 + kc * 32 + g * 8;
      half8 hh, ll;
#pragma unroll
      for (int e = 0; e < 8; ++e) {
        const float v = wr[e];
        const _Float16 hi = (_Float16)v;
        hh[e] = hi;
        ll[e] = (_Float16)(v - (float)hi);
      }
      ahi[tau][kc] = hh;
      alo[tau][kc] = ll;
    }
  }
  __syncthreads();

  // ---- stage steady LDS structures (reusing W'' space) ----
  char* sm = smem;
  for (int idx = tid; idx < (4 * 5120) / 4; idx += 512)
    ((float*)(sm + OFF_H))[idx] = 0.0f;  // zero both H buffers (h0 = 0)
  float* XL = (float*)(sm + OFF_X);
  for (int idx = tid; idx < NBW * TS; idx += 512) {
    const int bb = idx / TS, t = idx - bb * TS;
    XL[t * 33 + bb] = x[bbase * TS + idx];  // == x[(bbase+bb)*60 + t]
  }
  float* WL = (float*)(sm + OFF_WL);
  for (int idx = tid; idx < TS * 64; idx += 512) {
    const int t = idx >> 6, u = idx & 63;
    WL[idx] = (u < 50) ? w_lin[t * 50 + u] : 0.0f;
  }
  __syncthreads();

  char* H0 = sm + OFF_H;  // Hhi0 | Hlo0(+5120) | Hhi1(+10240) | Hlo1(+15360)
  const bool xwriter = (g == 3 && wm4 == 3);  // 32 lanes <-> 32 batches
  const bool hwriter = (g < 3) || (wm4 == 0);
  if (xwriter) {
    // ones row (k=62) in both buffers; x_0 (k=63) in buffer 0
    *(_Float16*)(H0 + b * 160 + hswz(b, 124)) = (_Float16)1.0f;
    *(_Float16*)(H0 + 10240 + b * 160 + hswz(b, 124)) = (_Float16)1.0f;
    const float xv = XL[b];
    const _Float16 xh = (_Float16)xv;
    *(_Float16*)(H0 + b * 160 + hswz(b, 126)) = xh;
    *(_Float16*)(H0 + 5120 + b * 160 + hswz(b, 126)) = (_Float16)(xv - (float)xh);
  }
  __syncthreads();

  float c[4] = {0.f, 0.f, 0.f, 0.f};
  float oacc = 0.0f;
  const int j0 = 16 * g + 4 * wm4;  // first unit owned by this lane
  const int g16 = g * 16;
  const int rb = b * 160;

#pragma unroll 1
  for (int t = 0; t < TS; ++t) {
    const char* RH = H0 + ((t & 1) ? 10240 : 0);
    char* WH = H0 + ((t & 1) ? 0 : 10240);
    // B-frags: lane reads H[b][k=32kc+8g .. +7] (hi and lo)
    const half8 bh0 = *(const half8*)(RH + rb + hswz(b, g16));
    const half8 bh1 = *(const half8*)(RH + rb + hswz(b, 64 + g16));
    const half8 bl0 = *(const half8*)(RH + 5120 + rb + hswz(b, g16));
    const half8 bl1 = *(const half8*)(RH + 5120 + rb + hswz(b, 64 + g16));
    f32x4 d[4];
#pragma unroll
    for (int tau = 0; tau < 4; ++tau) {
      f32x4 acc = {0.f, 0.f, 0.f, 0.f};
      acc = mfma16(ahi[tau][0], bh0, acc);
      acc = mfma16(ahi[tau][0], bl0, acc);
      acc = mfma16(alo[tau][0], bh0, acc);
      acc = mfma16(ahi[tau][1], bh1, acc);
      acc = mfma16(ahi[tau][1], bl1, acc);
      acc = mfma16(alo[tau][1], bh1, acc);
      d[tau] = acc;
    }
    const f32x4 wlv = *(const f32x4*)(WL + t * 64 + j0);
    half4 hh, hl;
#pragma unroll
    for (int tau = 0; tau < 4; ++tau) {
      const float ig = sigm(d[tau][0]);
      const float fg = sigm(d[tau][1]);
      const float gg = tanh_(d[tau][2]);
      const float og = sigm(d[tau][3]);
      const float cn = fmaf(fg, c[tau], ig * gg);
      c[tau] = cn;
      const float hn = og * tanh_(cn);
      oacc = fmaf(hn, wlv[tau], oacc);
      const _Float16 hhi = (_Float16)hn;
      hh[tau] = hhi;
      hl[tau] = (_Float16)(hn - (float)hhi);
    }
    if (hwriter) {
      *(half4*)(WH + rb + hswz(b, j0 * 2)) = hh;
      *(half4*)(WH + 5120 + rb + hswz(b, j0 * 2)) = hl;
    } else if (xwriter && t + 1 < TS) {
      const float xv = XL[(t + 1) * 33 + b];
      const _Float16 xh = (_Float16)xv;
      *(_Float16*)(WH + rb + hswz(b, 126)) = xh;
      *(_Float16*)(WH + 5120 + rb + hswz(b, 126)) = (_Float16)(xv - (float)xh);
    }
    __syncthreads();
  }

  // ---- output reduction: out[b] = b_lin + sum over 16 (g,wm4) groups ----
  float* OB = (float*)(sm + OFF_OB);
  OB[(g * 4 + wm4) * 32 + b] = oacc;
  __syncthreads();
  if (tid < NBW) {
    float s = b_lin[0];
#pragma unroll
    for (int q = 0; q < 16; ++q) s += OB[q * 32 + tid];
    out[bbase + tid] = s;
  }
}

extern "C" void kernel_launch(void* const* d_in, const int* in_sizes, int n_in,
                              void* d_out, int out_size, void* d_ws, size_t ws_size,
                              hipStream_t stream) {
  const float* x     = (const float*)d_in[0];
  const float* w_ih  = (const float*)d_in[1];
  const float* w_hh  = (const float*)d_in[2];
  const float* b_ih  = (const float*)d_in[3];
  const float* b_hh  = (const float*)d_in[4];
  const float* w_lin = (const float*)d_in[5];
  const float* b_lin = (const float*)d_in[6];
  float* out = (float*)d_out;

  dim3 grid(16384 / NBW);  // 512 WGs -> 2 per CU
  dim3 block(512);
  lstm_mfma<<<grid, block, 0, stream>>>(x, w_ih, w_hh, b_ih, b_hh, w_lin,
                                        b_lin, out);
}

// Round 4
// 118.738 us; speedup vs baseline: 4.0678x; 1.0359x over previous
//
#include <hip/hip_runtime.h>

// Fused LSTM B=16384, T=60, IN=1, H=50, OUT=1 — single-wave MFMA version.
// 1024 blocks x 64 threads: ONE WAVE owns 16 batches and ALL 208 gate rows
// -> the per-step h-exchange is intra-wave (LDS + waitcnt; __syncthreads on
// a 1-wave block is barrier-trivial). No inter-wave coupling at all.
// Weights: fp16 (hi only), 16 tiles x 2 K-chunks of A-fragments held in
// VGPRs (128 regs) — free because grid gives 1 wave/SIMD anyway.
// W'' row (T, 4g+reg) = orig row reg*50 + u, u = 16g + T (verified r3).
// K-cols: 0..49 = h (fp16), 62 = 1.0 (bias col), 63 = x. Lane (g,cl) owns
// units 16g..16g+15 for batch cl; writes them as one contiguous 16-half
// block (2 swizzled b128s). c-state fp32 in regs.

namespace {
constexpr int TS = 60;
constexpr int NBW = 16;  // batches per wave/block

typedef _Float16 half8 __attribute__((ext_vector_type(8)));
typedef float f32x4 __attribute__((ext_vector_type(4)));

__device__ __forceinline__ float fexp2(float x) { return __builtin_amdgcn_exp2f(x); }
__device__ __forceinline__ float frcp(float x) { return __builtin_amdgcn_rcpf(x); }
__device__ __forceinline__ float sigm(float x) {
  return frcp(1.0f + fexp2(-1.4426950408889634f * x));
}
__device__ __forceinline__ float tanh_(float x) {
  return fmaf(-2.0f, frcp(1.0f + fexp2(2.8853900817779268f * x)), 1.0f);
}
__device__ __forceinline__ f32x4 mfma16(half8 a, half8 b, f32x4 c) {
  return __builtin_amdgcn_mfma_f32_16x16x32_f16(a, b, c, 0, 0, 0);
}
}  // namespace

__global__ __launch_bounds__(64, 1) void lstm_wave(
    const float* __restrict__ x,      // [B][60]
    const float* __restrict__ w_ih,   // [200]
    const float* __restrict__ w_hh,   // [200][50]
    const float* __restrict__ b_ih,   // [200]
    const float* __restrict__ b_hh,   // [200]
    const float* __restrict__ w_lin,  // [3000]
    const float* __restrict__ b_lin,  // [1]
    float* __restrict__ out)          // [B]
{
  __shared__ __align__(16) _Float16 HB[2][NBW * 64];  // 2 x 2 KB, swizzled
  __shared__ __align__(16) float WL[TS * 64];         // 15.4 KB, 0-padded
  __shared__ __align__(16) float XL[TS * NBW];        // 3.75 KB [t][b]

  const int lane = threadIdx.x;  // 0..63
  const int g = lane >> 4;       // k-group (B-frag) / unit-block (D)
  const int cl = lane & 15;      // batch-in-wave; also A-fragment M-row
  const long bbase = (long)blockIdx.x * NBW;

  // ---- stage XL[t][b] (coalesced read of this block's x slice) ----
  for (int i = lane; i < TS * NBW; i += 64) {
    const int b = i / TS, t = i - b * TS;
    XL[t * NBW + b] = x[bbase * TS + i];
  }
  // ---- stage WL[t][u] (u<50 else 0) ----
  for (int i = lane; i < TS * 64; i += 64) {
    const int t = i >> 6, u = i & 63;
    WL[i] = (u < 50) ? w_lin[t * 50 + u] : 0.0f;
  }

  // ---- gather A-fragments from global (fp32 -> fp16), once ----
  // lane (g,cl), tile T: A-row = cl -> orig = (cl&3)*50 + 16*(cl>>2) + T;
  // k = kc*32 + 8g + e. Specials: k==62 -> bias, k==63 -> w_ih.
  half8 A[16][2];
  {
    const int regA = cl & 3, gA = cl >> 2;
#pragma unroll
    for (int T = 0; T < 16; ++T) {
      const int u = 16 * gA + T;
      const int orig = regA * 50 + u;
#pragma unroll
      for (int kc = 0; kc < 2; ++kc) {
        half8 frag;
        const int k0 = kc * 32 + 8 * g;
#pragma unroll
        for (int e = 0; e < 8; ++e) {
          const int k = k0 + e;
          float v = 0.0f;
          if (u < 50) {
            if (k < 50) v = w_hh[orig * 50 + k];
            else if (k == 62) v = b_ih[orig] + b_hh[orig];
            else if (k == 63) v = w_ih[orig];
          }
          frag[e] = (_Float16)v;
        }
        A[T][kc] = frag;
      }
    }
  }

  // ---- swizzled half-index within H row (row = cl, 8 chunks of 16 B) ----
  auto swzi = [&](int k) {
    return cl * 64 + ((((k >> 3) ^ (cl & 7)) << 3) | (k & 7));
  };
  const int rk0 = swzi(8 * g);        // B-frag kc0 read
  const int rk1 = swzi(32 + 8 * g);   // B-frag kc1 read
  const int wk0 = swzi(16 * g);       // h-block write (first 8 halves)
  const int wk1 = swzi(16 * g + 8);   // h-block write (second 8 halves)

  __syncthreads();  // XL ready (needed for init below)

  // ---- init buffer 0: h=0; g==3 sets k=62 -> 1.0, k=63 -> x_0 ----
  {
    half8 z = {};
    half8 z1 = {};
    if (g == 3) {
      z1[6] = (_Float16)1.0f;
      z1[7] = (_Float16)XL[0 * NBW + cl];
    }
    *(half8*)&HB[0][wk0] = z;
    *(half8*)&HB[0][wk1] = z1;
  }
  __syncthreads();

  float c[16];
#pragma unroll
  for (int T = 0; T < 16; ++T) c[T] = 0.0f;
  float oacc = 0.0f;

  auto step = [&](int t, const _Float16* RH, _Float16* WH) {
    const half8 B0 = *(const half8*)&RH[rk0];
    const half8 B1 = *(const half8*)&RH[rk1];
    half8 hh0, hh1;
#pragma unroll
    for (int hf = 0; hf < 2; ++hf) {
      f32x4 acc[8];
#pragma unroll
      for (int q = 0; q < 8; ++q) {
        const int T = hf * 8 + q;
        f32x4 a = {0.f, 0.f, 0.f, 0.f};
        a = mfma16(A[T][0], B0, a);
        a = mfma16(A[T][1], B1, a);
        acc[q] = a;
      }
      const f32x4 wl0 = *(const f32x4*)&WL[t * 64 + 16 * g + hf * 8];
      const f32x4 wl1 = *(const f32x4*)&WL[t * 64 + 16 * g + hf * 8 + 4];
#pragma unroll
      for (int q = 0; q < 8; ++q) {
        const int T = hf * 8 + q;
        const float ig = sigm(acc[q][0]);
        const float fg = sigm(acc[q][1]);
        const float gg = tanh_(acc[q][2]);
        const float og = sigm(acc[q][3]);
        const float cn = fmaf(fg, c[T], ig * gg);
        c[T] = cn;
        const float hn = og * tanh_(cn);
        oacc = fmaf(hn, (q < 4) ? wl0[q] : wl1[q - 4], oacc);
        if (hf == 0) hh0[q] = (_Float16)hn;
        else hh1[q] = (_Float16)hn;
      }
    }
    if (g == 3) {  // refresh ones/x columns (slots k=62,63 of this block)
      hh1[6] = (_Float16)1.0f;
      const int tn = (t + 1 < TS) ? (t + 1) : (TS - 1);
      hh1[7] = (_Float16)XL[tn * NBW + cl];
    }
    *(half8*)&WH[wk0] = hh0;
    *(half8*)&WH[wk1] = hh1;
    __syncthreads();  // 1-wave block: compiles to waitcnt-only ordering
  };

#pragma unroll 1
  for (int t = 0; t < TS; t += 2) {
    step(t, HB[0], HB[1]);
    step(t + 1, HB[1], HB[0]);
  }

  // ---- reduce oacc over the 4 lane groups (units are split by g) ----
  oacc += __shfl_xor(oacc, 32);
  oacc += __shfl_xor(oacc, 16);
  if (lane < NBW) out[bbase + lane] = oacc + b_lin[0];
}

extern "C" void kernel_launch(void* const* d_in, const int* in_sizes, int n_in,
                              void* d_out, int out_size, void* d_ws, size_t ws_size,
                              hipStream_t stream) {
  const float* x     = (const float*)d_in[0];
  const float* w_ih  = (const float*)d_in[1];
  const float* w_hh  = (const float*)d_in[2];
  const float* b_ih  = (const float*)d_in[3];
  const float* b_hh  = (const float*)d_in[4];
  const float* w_lin = (const float*)d_in[5];
  const float* b_lin = (const float*)d_in[6];
  float* out = (float*)d_out;

  dim3 grid(16384 / NBW);  // 1024 single-wave blocks -> 1 per SIMD
  dim3 block(64);
  lstm_wave<<<grid, block, 0, stream>>>(x, w_ih, w_hh, b_ih, b_hh, w_lin,
                                        b_lin, out);
}

// Round 5
// 98.513 us; speedup vs baseline: 4.9029x; 1.2053x over previous
//
#include <hip/hip_runtime.h>

// Fused LSTM B=16384, T=60, IN=1, H=50, OUT=1 — 4-wave MFMA version.
// 1024 blocks x 256 threads (4 waves). Block owns 16 batches; wave w owns
// M-tiles 4w..4w+3 (units 16g+4w+tau for lane group g). h-exchange via one
// __syncthreads per step; 4 blocks/CU -> 4 waves/SIMD for latency hiding
// (round-4's 1 wave/SIMD exposed the full dependency chain: 75% stall).
// Weights fp16(hi), A-frags in VGPRs (32 regs). K-cols: 0..49=h, 62=1(bias),
// 63=x. D-frag: lane(g,cl) tile T holds gates i,f,g,o of unit 16g+T, batch
// cl -> elementwise register-local. H fp16 [b][64] XOR-swizzled, dbuf.

namespace {
constexpr int TS = 60;
constexpr int NBW = 16;  // batches per block

typedef _Float16 half8 __attribute__((ext_vector_type(8)));
typedef _Float16 half4 __attribute__((ext_vector_type(4)));
typedef float f32x4 __attribute__((ext_vector_type(4)));

__device__ __forceinline__ float fexp2(float x) { return __builtin_amdgcn_exp2f(x); }
__device__ __forceinline__ float frcp(float x) { return __builtin_amdgcn_rcpf(x); }
__device__ __forceinline__ float sigm(float x) {
  return frcp(1.0f + fexp2(-1.4426950408889634f * x));
}
__device__ __forceinline__ float tanh_(float x) {
  return fmaf(-2.0f, frcp(1.0f + fexp2(2.8853900817779268f * x)), 1.0f);
}
__device__ __forceinline__ f32x4 mfma16(half8 a, half8 b, f32x4 c) {
  return __builtin_amdgcn_mfma_f32_16x16x32_f16(a, b, c, 0, 0, 0);
}
}  // namespace

__global__ __launch_bounds__(256, 4) void lstm_w4(
    const float* __restrict__ x,      // [B][60]
    const float* __restrict__ w_ih,   // [200]
    const float* __restrict__ w_hh,   // [200][50]
    const float* __restrict__ b_ih,   // [200]
    const float* __restrict__ b_hh,   // [200]
    const float* __restrict__ w_lin,  // [3000]
    const float* __restrict__ b_lin,  // [1]
    float* __restrict__ out)          // [B]
{
  __shared__ __align__(16) _Float16 HB[2][NBW * 64];  // 2 x 2 KB, swizzled
  __shared__ __align__(16) float WL[TS * 64];         // 15.4 KB, 0-padded
  __shared__ __align__(16) float XL[TS * NBW];        // 3.75 KB [t][b]
  __shared__ float OB[4 * NBW];                       // output partials

  const int tid = threadIdx.x;
  const int lane = tid & 63;
  const int wv = tid >> 6;  // wave 0..3 (uniform within wave)
  const int g = lane >> 4;  // lane quad-group
  const int cl = lane & 15; // batch-in-block; also A-frag M-row
  const long bbase = (long)blockIdx.x * NBW;

  // ---- stage XL[t][b] (coalesced) ----
  for (int i = tid; i < TS * NBW; i += 256) {
    const int b = i / TS, t = i - b * TS;
    XL[t * NBW + b] = x[bbase * TS + i];
  }
  // ---- stage WL[t][u] (u<50 else 0) ----
  for (int i = tid; i < TS * 64; i += 256) {
    const int t = i >> 6, u = i & 63;
    WL[i] = (u < 50) ? w_lin[t * 50 + u] : 0.0f;
  }

  // ---- gather this wave's A-fragments (fp32 -> fp16), once ----
  // tile T=4wv+tau: A-row cl -> orig row (cl&3)*50 + 16*(cl>>2) + T;
  // element e -> k = kc*32 + 8g + e. k==62 -> bias, k==63 -> w_ih.
  half8 A[4][2];
  {
    const int regA = cl & 3, gA = cl >> 2;
#pragma unroll
    for (int tau = 0; tau < 4; ++tau) {
      const int T = 4 * wv + tau;
      const int uA = 16 * gA + T;
      const int orig = regA * 50 + uA;
#pragma unroll
      for (int kc = 0; kc < 2; ++kc) {
        half8 frag;
        const int k0 = kc * 32 + 8 * g;
#pragma unroll
        for (int e = 0; e < 8; ++e) {
          const int k = k0 + e;
          float v = 0.0f;
          if (uA < 50) {
            if (k < 50) v = w_hh[orig * 50 + k];
            else if (k == 62) v = b_ih[orig] + b_hh[orig];
            else if (k == 63) v = w_ih[orig];
          }
          frag[e] = (_Float16)v;
        }
        A[tau][kc] = frag;
      }
    }
  }

  // swizzled half-index within H: row cl (64 halves), 8 chunks of 8 halves,
  // chunk XOR (cl&7). Reads are chunk-aligned b128; write is a half4 at
  // chunk-offset 0 or 4.
  auto swzi = [&](int k) {
    return cl * 64 + ((((k >> 3) ^ (cl & 7)) << 3) | (k & 7));
  };
  const int rk0 = swzi(8 * g);
  const int rk1 = swzi(32 + 8 * g);
  const int wk = swzi(16 * g + 4 * wv);

  __syncthreads();  // XL ready

  // ---- init buffer 0: h=0; wave3/g3 lanes own k=60..63 -> set 1.0, x_0 ----
  {
    half4 z = {};
    if (wv == 3 && g == 3) {
      z[2] = (_Float16)1.0f;          // k=62
      z[3] = (_Float16)XL[cl];        // k=63 = x_0
    }
    *(half4*)&HB[0][wk] = z;
  }
  __syncthreads();

  float c[4] = {0.f, 0.f, 0.f, 0.f};
  float oacc = 0.0f;

  auto step = [&](int t, const _Float16* RH, _Float16* WH) {
    const half8 B0 = *(const half8*)&RH[rk0];
    const half8 B1 = *(const half8*)&RH[rk1];
    f32x4 acc[4];
#pragma unroll
    for (int tau = 0; tau < 4; ++tau) {
      f32x4 a = {0.f, 0.f, 0.f, 0.f};
      a = mfma16(A[tau][0], B0, a);
      a = mfma16(A[tau][1], B1, a);
      acc[tau] = a;
    }
    const f32x4 wl = *(const f32x4*)&WL[t * 64 + 16 * g + 4 * wv];
    half4 hh;
#pragma unroll
    for (int tau = 0; tau < 4; ++tau) {
      const float ig = sigm(acc[tau][0]);
      const float fg = sigm(acc[tau][1]);
      const float gg = tanh_(acc[tau][2]);
      const float og = sigm(acc[tau][3]);
      const float cn = fmaf(fg, c[tau], ig * gg);
      c[tau] = cn;
      const float hn = og * tanh_(cn);
      oacc = fmaf(hn, wl[tau], oacc);
      hh[tau] = (_Float16)hn;
    }
    if (wv == 3 && g == 3) {  // refresh ones/x columns (k=62,63)
      hh[2] = (_Float16)1.0f;
      const int tn = (t + 1 < TS) ? (t + 1) : (TS - 1);
      hh[3] = (_Float16)XL[tn * NBW + cl];
    }
    *(half4*)&WH[wk] = hh;
    __syncthreads();
  };

#pragma unroll 1
  for (int t = 0; t < TS; t += 2) {
    step(t, HB[0], HB[1]);
    step(t + 1, HB[1], HB[0]);
  }

  // ---- reduce: sum over g within wave, then over waves via LDS ----
  oacc += __shfl_xor(oacc, 32);
  oacc += __shfl_xor(oacc, 16);
  if (lane < NBW) OB[wv * NBW + lane] = oacc;
  __syncthreads();
  if (tid < NBW) {
    float s = b_lin[0];
#pragma unroll
    for (int q = 0; q < 4; ++q) s += OB[q * NBW + tid];
    out[bbase + tid] = s;
  }
}

extern "C" void kernel_launch(void* const* d_in, const int* in_sizes, int n_in,
                              void* d_out, int out_size, void* d_ws, size_t ws_size,
                              hipStream_t stream) {
  const float* x     = (const float*)d_in[0];
  const float* w_ih  = (const float*)d_in[1];
  const float* w_hh  = (const float*)d_in[2];
  const float* b_ih  = (const float*)d_in[3];
  const float* b_hh  = (const float*)d_in[4];
  const float* w_lin = (const float*)d_in[5];
  const float* b_lin = (const float*)d_in[6];
  float* out = (float*)d_out;

  dim3 grid(16384 / NBW);  // 1024 blocks x 4 waves -> 4 waves/SIMD
  dim3 block(256);
  lstm_w4<<<grid, block, 0, stream>>>(x, w_ih, w_hh, b_ih, b_hh, w_lin,
                                      b_lin, out);
}

// Round 6
// 93.059 us; speedup vs baseline: 5.1903x; 1.0586x over previous
//
#include <hip/hip_runtime.h>

// Fused LSTM B=16384, T=60, IN=1, H=50, OUT=1 — 4-wave, dual-group MFMA.
// 512 blocks x 256 thr (4 waves). Block owns 32 batches = two INDEPENDENT
// 16-batch groups A/B with separate H double-buffers; each wave owns M-tiles
// 4wv..4wv+3 for BOTH groups -> two interleavable dependency chains per wave
// (fills MFMA + transcendental latency at instruction granularity), and one
// barrier serves both groups (halved barrier count per work). Weights fp16
// (hi), A-frags in VGPRs, shared across groups. K-cols: 0..49=h, 62=1(bias),
// 63=x. H fp16 [b][64] XOR-swizzled. Round-5 was stall-bound: wall 4283
// cyc/step vs ~1100 issue — chains/SIMD and chain-fill are the lever.

namespace {
constexpr int TS = 60;
constexpr int NBW = 32;  // batches per block (2 groups of 16)

typedef _Float16 half8 __attribute__((ext_vector_type(8)));
typedef _Float16 half4 __attribute__((ext_vector_type(4)));
typedef float f32x4 __attribute__((ext_vector_type(4)));

__device__ __forceinline__ float fexp2(float x) { return __builtin_amdgcn_exp2f(x); }
__device__ __forceinline__ float frcp(float x) { return __builtin_amdgcn_rcpf(x); }
__device__ __forceinline__ float sigm(float x) {
  return frcp(1.0f + fexp2(-1.4426950408889634f * x));
}
__device__ __forceinline__ float tanh_(float x) {
  return fmaf(-2.0f, frcp(1.0f + fexp2(2.8853900817779268f * x)), 1.0f);
}
__device__ __forceinline__ f32x4 mfma16(half8 a, half8 b, f32x4 c) {
  return __builtin_amdgcn_mfma_f32_16x16x32_f16(a, b, c, 0, 0, 0);
}
}  // namespace

__global__ __launch_bounds__(256, 2) void lstm_w4x2(
    const float* __restrict__ x,      // [B][60]
    const float* __restrict__ w_ih,   // [200]
    const float* __restrict__ w_hh,   // [200][50]
    const float* __restrict__ b_ih,   // [200]
    const float* __restrict__ b_hh,   // [200]
    const float* __restrict__ w_lin,  // [3000]
    const float* __restrict__ b_lin,  // [1]
    float* __restrict__ out)          // [B]
{
  __shared__ __align__(16) _Float16 HA[2][16 * 64];  // group A dbuf, swizzled
  __shared__ __align__(16) _Float16 HBf[2][16 * 64]; // group B dbuf
  __shared__ __align__(16) float WL[TS * 64];        // 15.4 KB, 0-padded
  __shared__ __align__(16) float XL[TS * NBW];       // 7.5 KB [t][b 0..31]
  __shared__ float OB[4][2][16];

  const int tid = threadIdx.x;
  const int lane = tid & 63;
  const int wv = tid >> 6;   // 0..3
  const int g = lane >> 4;   // lane quad-group
  const int cl = lane & 15;  // batch-in-group; A-frag M-row
  const long bbase = (long)blockIdx.x * NBW;

  // ---- stage XL[t][b] (coalesced over the block's 32x60 slice) ----
  for (int i = tid; i < TS * NBW; i += 256) {
    const int b = i / TS, t = i - b * TS;
    XL[t * NBW + b] = x[bbase * TS + i];
  }
  // ---- stage WL[t][u] (u<50 else 0) ----
  for (int i = tid; i < TS * 64; i += 256) {
    const int t = i >> 6, u = i & 63;
    WL[i] = (u < 50) ? w_lin[t * 50 + u] : 0.0f;
  }

  // ---- gather this wave's A-fragments (fp32 -> fp16), once ----
  half8 A[4][2];
  {
    const int regA = cl & 3, gA = cl >> 2;
#pragma unroll
    for (int tau = 0; tau < 4; ++tau) {
      const int T = 4 * wv + tau;
      const int uA = 16 * gA + T;
      const int orig = regA * 50 + uA;
#pragma unroll
      for (int kc = 0; kc < 2; ++kc) {
        half8 frag;
        const int k0 = kc * 32 + 8 * g;
#pragma unroll
        for (int e = 0; e < 8; ++e) {
          const int k = k0 + e;
          float v = 0.0f;
          if (uA < 50) {
            if (k < 50) v = w_hh[orig * 50 + k];
            else if (k == 62) v = b_ih[orig] + b_hh[orig];
            else if (k == 63) v = w_ih[orig];
          }
          frag[e] = (_Float16)v;
        }
        A[tau][kc] = frag;
      }
    }
  }

  // swizzled half-index within H row (row cl, 8 chunks of 8 halves, XOR cl&7)
  auto swzi = [&](int k) {
    return cl * 64 + ((((k >> 3) ^ (cl & 7)) << 3) | (k & 7));
  };
  const int rk0 = swzi(8 * g);
  const int rk1 = swzi(32 + 8 * g);
  const int wk = swzi(16 * g + 4 * wv);

  __syncthreads();  // XL ready

  // ---- init buffer 0 of both groups: h=0, k=62 -> 1.0, k=63 -> x_0 ----
  {
    half4 z0 = {}, z1 = {};
    if (wv == 3 && g == 3) {
      z0[2] = (_Float16)1.0f;
      z0[3] = (_Float16)XL[cl];         // group A x_0
      z1[2] = (_Float16)1.0f;
      z1[3] = (_Float16)XL[16 + cl];    // group B x_0
    }
    *(half4*)&HA[0][wk] = z0;
    *(half4*)&HBf[0][wk] = z1;
  }
  __syncthreads();

  float ca[4] = {0.f, 0.f, 0.f, 0.f};
  float cb[4] = {0.f, 0.f, 0.f, 0.f};
  float oa = 0.0f, ob = 0.0f;

#pragma unroll 1
  for (int t = 0; t < TS; ++t) {
    const int p = t & 1;
    const _Float16* RA = HA[p];
    _Float16* WA = HA[p ^ 1];
    const _Float16* RB = HBf[p];
    _Float16* WB = HBf[p ^ 1];

    const half8 Ba0 = *(const half8*)&RA[rk0];
    const half8 Ba1 = *(const half8*)&RA[rk1];
    const half8 Bb0 = *(const half8*)&RB[rk0];
    const half8 Bb1 = *(const half8*)&RB[rk1];

    f32x4 da[4], db[4];
#pragma unroll
    for (int tau = 0; tau < 4; ++tau) {
      f32x4 a = {0.f, 0.f, 0.f, 0.f};
      a = mfma16(A[tau][0], Ba0, a);
      a = mfma16(A[tau][1], Ba1, a);
      da[tau] = a;
      f32x4 b = {0.f, 0.f, 0.f, 0.f};
      b = mfma16(A[tau][0], Bb0, b);
      b = mfma16(A[tau][1], Bb1, b);
      db[tau] = b;
    }

    const f32x4 wl = *(const f32x4*)&WL[t * 64 + 16 * g + 4 * wv];
    half4 ha, hb;
#pragma unroll
    for (int tau = 0; tau < 4; ++tau) {
      {
        const float ig = sigm(da[tau][0]);
        const float fg = sigm(da[tau][1]);
        const float gg = tanh_(da[tau][2]);
        const float og = sigm(da[tau][3]);
        const float cn = fmaf(fg, ca[tau], ig * gg);
        ca[tau] = cn;
        const float hn = og * tanh_(cn);
        oa = fmaf(hn, wl[tau], oa);
        ha[tau] = (_Float16)hn;
      }
      {
        const float ig = sigm(db[tau][0]);
        const float fg = sigm(db[tau][1]);
        const float gg = tanh_(db[tau][2]);
        const float og = sigm(db[tau][3]);
        const float cn = fmaf(fg, cb[tau], ig * gg);
        cb[tau] = cn;
        const float hn = og * tanh_(cn);
        ob = fmaf(hn, wl[tau], ob);
        hb[tau] = (_Float16)hn;
      }
    }
    if (wv == 3 && g == 3) {  // refresh ones/x columns (k=62,63)
      const int tn = (t + 1 < TS) ? (t + 1) : (TS - 1);
      ha[2] = (_Float16)1.0f;
      ha[3] = (_Float16)XL[tn * NBW + cl];
      hb[2] = (_Float16)1.0f;
      hb[3] = (_Float16)XL[tn * NBW + 16 + cl];
    }
    *(half4*)&WA[wk] = ha;
    *(half4*)&WB[wk] = hb;
    __syncthreads();
  }

  // ---- reduce over lane groups, then over waves ----
  oa += __shfl_xor(oa, 32);
  oa += __shfl_xor(oa, 16);
  ob += __shfl_xor(ob, 32);
  ob += __shfl_xor(ob, 16);
  if (lane < 16) {
    OB[wv][0][lane] = oa;
    OB[wv][1][lane] = ob;
  }
  __syncthreads();
  if (tid < 32) {
    const int grp = tid >> 4, b = tid & 15;
    float s = b_lin[0];
#pragma unroll
    for (int q = 0; q < 4; ++q) s += OB[q][grp][b];
    out[bbase + grp * 16 + b] = s;
  }
}

extern "C" void kernel_launch(void* const* d_in, const int* in_sizes, int n_in,
                              void* d_out, int out_size, void* d_ws, size_t ws_size,
                              hipStream_t stream) {
  const float* x     = (const float*)d_in[0];
  const float* w_ih  = (const float*)d_in[1];
  const float* w_hh  = (const float*)d_in[2];
  const float* b_ih  = (const float*)d_in[3];
  const float* b_hh  = (const float*)d_in[4];
  const float* w_lin = (const float*)d_in[5];
  const float* b_lin = (const float*)d_in[6];
  float* out = (float*)d_out;

  dim3 grid(16384 / NBW);  // 512 blocks -> 2 per CU
  dim3 block(256);
  lstm_w4x2<<<grid, block, 0, stream>>>(x, w_ih, w_hh, b_ih, b_hh, w_lin,
                                        b_lin, out);
}